// Round 3
// baseline (144.989 us; speedup 1.0000x reference)
//
#include <hip/hip_runtime.h>

constexpr int B_ = 32, C_ = 256, H_ = 32, W_ = 32, M_ = 1024;
constexpr int NH = 4, DK = 16, DV = 64;
constexpr float EPS = 1e-5f;

// ---------------- Kernel 1: qkv = W(144x256) @ x(256xM) per batch, + BN ----
// grid: 32 b * 16 m-tiles of 64.  block 256: ml=tid&15 (4 consecutive m each),
// og=tid>>4 (9 o each, stride 16).  LDS: x-tile fp32 [64c][64m], W [144][64c].
__global__ __launch_bounds__(256) void k_qkv(
    const float* __restrict__ x, const float* __restrict__ w,
    const float* __restrict__ qg, const float* __restrict__ qb,
    const float* __restrict__ qm, const float* __restrict__ qv,
    const float* __restrict__ vg, const float* __restrict__ vb,
    const float* __restrict__ vm, const float* __restrict__ vv,
    float* __restrict__ q_out, float* __restrict__ k_out,
    float* __restrict__ v_out)
{
    __shared__ float xs[64][64];    // 16 KB
    __shared__ float wsh[144][64];  // 36.9 KB
    const int b   = blockIdx.x >> 4;
    const int m0  = (blockIdx.x & 15) * 64;
    const int tid = threadIdx.x;
    const int ml  = tid & 15;
    const int og  = tid >> 4;

    float acc[4][9];
#pragma unroll
    for (int i = 0; i < 4; i++)
#pragma unroll
        for (int j = 0; j < 9; j++) acc[i][j] = 0.f;

    for (int c0 = 0; c0 < C_; c0 += 64) {
        __syncthreads();
#pragma unroll
        for (int i = 0; i < 4; i++) {            // 4096 x = 1024 float4
            int f4 = tid + 256 * i;
            int ci = f4 >> 4, mf = (f4 & 15) * 4;
            *reinterpret_cast<float4*>(&xs[ci][mf]) =
                *reinterpret_cast<const float4*>(&x[(b * C_ + c0 + ci) * M_ + m0 + mf]);
        }
#pragma unroll
        for (int i = 0; i < 9; i++) {            // 9216 w = 2304 float4
            int f4 = tid + 256 * i;
            int o = f4 >> 4, cf = (f4 & 15) * 4;
            *reinterpret_cast<float4*>(&wsh[o][cf]) =
                *reinterpret_cast<const float4*>(&w[o * C_ + c0 + cf]);
        }
        __syncthreads();
#pragma unroll 2
        for (int ci = 0; ci < 64; ci++) {
            float4 xv = *reinterpret_cast<const float4*>(&xs[ci][ml * 4]);
#pragma unroll
            for (int j = 0; j < 9; j++) {
                float wv = wsh[og + 16 * j][ci];
                acc[0][j] = fmaf(wv, xv.x, acc[0][j]);
                acc[1][j] = fmaf(wv, xv.y, acc[1][j]);
                acc[2][j] = fmaf(wv, xv.z, acc[2][j]);
                acc[3][j] = fmaf(wv, xv.w, acc[3][j]);
            }
        }
    }

    const int mbase = m0 + ml * 4;
#pragma unroll
    for (int j = 0; j < 9; j++) {
        const int o = og + 16 * j;
        if (o < 64) {                         // q channel: BN then [b][m][n][k]
            float inv = qg[o] * rsqrtf(qv[o] + EPS);
            float add = qb[o] - qm[o] * inv;
            int n = o >> 4, k = o & 15;
#pragma unroll
            for (int i = 0; i < 4; i++)
                q_out[((b * M_ + mbase + i) * NH + n) * DK + k] =
                    acc[i][j] * inv + add;
        } else if (o < 80) {                  // k logits: [b][k][m]
            int kk = o - 64;
#pragma unroll
            for (int i = 0; i < 4; i++)
                k_out[(b * DK + kk) * M_ + mbase + i] = acc[i][j];
        } else {                              // v channel: BN then [b][m][vd]
            int vd = o - 80;
            float inv = vg[vd] * rsqrtf(vv[vd] + EPS);
            float add = vb[vd] - vm[vd] * inv;
#pragma unroll
            for (int i = 0; i < 4; i++)
                v_out[(b * M_ + mbase + i) * DV + vd] = acc[i][j] * inv + add;
        }
    }
}

// ---------------- Kernel 2: softmax over M per (b,k) row, in place ---------
__global__ __launch_bounds__(256) void k_softmax(float* __restrict__ kl)
{
    float* p = kl + (size_t)blockIdx.x * M_;
    const int tid = threadIdx.x;
    float v[4];
    float mx = -1e30f;
#pragma unroll
    for (int i = 0; i < 4; i++) { v[i] = p[tid + 256 * i]; mx = fmaxf(mx, v[i]); }
#pragma unroll
    for (int off = 32; off >= 1; off >>= 1) mx = fmaxf(mx, __shfl_xor(mx, off));
    __shared__ float red[8];
    if ((tid & 63) == 0) red[tid >> 6] = mx;
    __syncthreads();
    mx = fmaxf(fmaxf(red[0], red[1]), fmaxf(red[2], red[3]));
    float s = 0.f;
#pragma unroll
    for (int i = 0; i < 4; i++) { v[i] = __expf(v[i] - mx); s += v[i]; }
#pragma unroll
    for (int off = 32; off >= 1; off >>= 1) s += __shfl_xor(s, off);
    if ((tid & 63) == 0) red[4 + (tid >> 6)] = s;
    __syncthreads();
    s = red[4] + red[5] + red[6] + red[7];
    float inv = 1.f / s;
#pragma unroll
    for (int i = 0; i < 4; i++) p[tid + 256 * i] = v[i] * inv;
}

// ---------------- Kernel 3: content_lam[b,k,vd] = sum_m ksm * v ------------
// grid 32 b * 8 m-chunks of 128; thread: vd=tid&63, kq=tid>>6 -> k=kq+4j.
// ksm loads are wave-uniform (broadcast); vbn loads coalesced. atomicAdd out.
__global__ __launch_bounds__(256) void k_clam(
    const float* __restrict__ ksm, const float* __restrict__ vbn,
    float* __restrict__ clam)
{
    const int b   = blockIdx.x >> 3;
    const int m0  = (blockIdx.x & 7) * 128;
    const int tid = threadIdx.x;
    const int vd  = tid & 63;
    const int kq  = tid >> 6;
    float acc[4] = {0.f, 0.f, 0.f, 0.f};
    for (int mi = 0; mi < 128; mi++) {
        const int m = m0 + mi;
        const float vvv = vbn[(b * M_ + m) * DV + vd];
#pragma unroll
        for (int j = 0; j < 4; j++)
            acc[j] = fmaf(ksm[(b * DK + kq + 4 * j) * M_ + m], vvv, acc[j]);
    }
#pragma unroll
    for (int j = 0; j < 4; j++)
        atomicAdd(&clam[(b * DK + kq + 4 * j) * DV + vd], acc[j]);
}

// ---------------- Kernel 4: fused 7x7 conv (pos_lam) + final matmul --------
// grid 32 b * 8 row-tiles (4 rows = 128 px).  512 thr: vd=tid&63, pg=tid>>6.
// v halo (10 rows) in LDS fp32 [row][col][vd] (lane=vd -> conflict-free).
// plam[4px][16k] in regs; lam_w broadcast from LDS (wave-uniform).
// out = q . (clam + lb + plam), staged via LDS (stride 260 -> 16B-aligned
// float4 rows) -> coalesced float4 writes.
__global__ __launch_bounds__(512) void k_fuse(
    const float* __restrict__ vbn, const float* __restrict__ qbn,
    const float* __restrict__ clam,
    const float* __restrict__ lw, const float* __restrict__ lb,
    float* __restrict__ out)
{
    __shared__ float v_s[10 * 32 * 64];    // 80 KB
    __shared__ float ostage[64][260];      // 66.6 KB, stride%4==0 (b128 ok)
    __shared__ float lw_s[16 * 49];
    __shared__ float cl_s[16 * 64];
    __shared__ float lb_s[16];

    const int b   = blockIdx.x >> 3;
    const int rt  = blockIdx.x & 7;
    const int h0  = rt * 4;
    const int tid = threadIdx.x;

    for (int i4 = tid; i4 < 5120; i4 += 512) {   // 20480 floats as float4
        int r   = i4 >> 9;                 // staged row 0..9 = global h0-3+r
        int rem = (i4 & 511) * 4;          // (col*64+vd) float offset
        int gr  = h0 - 3 + r;
        float4 val = make_float4(0.f, 0.f, 0.f, 0.f);
        if (gr >= 0 && gr < H_)
            val = *reinterpret_cast<const float4*>(&vbn[(b * M_ + gr * W_) * DV + rem]);
        *reinterpret_cast<float4*>(&v_s[r * 2048 + rem]) = val;
    }
    for (int i = tid; i < 784; i += 512) lw_s[i] = lw[i];
    if (tid < 256)
        *reinterpret_cast<float4*>(&cl_s[tid * 4]) =
            *reinterpret_cast<const float4*>(&clam[b * DK * DV + tid * 4]);
    if (tid < 16) lb_s[tid] = lb[tid];
    __syncthreads();

    const int vd  = tid & 63;
    const int pg  = tid >> 6;       // wave index: pixel column group
    const int px0 = pg * 4;

    for (int grp = 0; grp < 4; grp++) {     // grp = pixel row within tile
        float plam[4][16];
#pragma unroll
        for (int ip = 0; ip < 4; ip++)
#pragma unroll
            for (int k = 0; k < 16; k++) plam[ip][k] = 0.f;

        for (int dy = 0; dy < 7; dy++) {
            const int rowoff = (grp + dy) * W_;   // staged row index * 32
#pragma unroll
            for (int dx = 0; dx < 7; dx++) {
                float lwv[16];
#pragma unroll
                for (int k = 0; k < 16; k++) lwv[k] = lw_s[k * 49 + dy * 7 + dx];
#pragma unroll
                for (int ip = 0; ip < 4; ip++) {
                    const int col = px0 + ip + dx - 3;
                    float vval = 0.f;
                    if (col >= 0 && col < W_)      // wave-uniform branch
                        vval = v_s[(rowoff + col) * DV + vd];
#pragma unroll
                    for (int k = 0; k < 16; k++)
                        plam[ip][k] = fmaf(vval, lwv[k], plam[ip][k]);
                }
            }
        }
        // epilogue: 4 pixels of this group
#pragma unroll
        for (int ip = 0; ip < 4; ip++) {
            const int p = grp * 32 + px0 + ip;     // 0..127 within tile
            const int m = h0 * W_ + p;
            float lamv[16];
#pragma unroll
            for (int k = 0; k < 16; k++)
                lamv[k] = plam[ip][k] + cl_s[k * DV + vd] + lb_s[k];
            const float* qp = qbn + (size_t)(b * M_ + m) * NH * DK;
            float4 ov;
            float* ovp = reinterpret_cast<float*>(&ov);
#pragma unroll
            for (int n = 0; n < 4; n++) {
                const float4* q4 = reinterpret_cast<const float4*>(qp + n * DK);
                float4 qa = q4[0], qb4 = q4[1], qc = q4[2], qd = q4[3];
                ovp[n] = qa.x * lamv[0] + qa.y * lamv[1] + qa.z * lamv[2] + qa.w * lamv[3]
                       + qb4.x * lamv[4] + qb4.y * lamv[5] + qb4.z * lamv[6] + qb4.w * lamv[7]
                       + qc.x * lamv[8] + qc.y * lamv[9] + qc.z * lamv[10] + qc.w * lamv[11]
                       + qd.x * lamv[12] + qd.y * lamv[13] + qd.z * lamv[14] + qd.w * lamv[15];
            }
            *reinterpret_cast<float4*>(&ostage[vd][(p & 63) * 4]) = ov;
        }
        if (grp & 1) {                      // flush 64 pixels, coalesced
            __syncthreads();
            const int half = grp >> 1;
            const int mb4 = (h0 + half * 2) * W_ * 4;
            for (int i = tid; i < 64 * 64; i += 512) {
                const int vdw  = i >> 6;
                const int off4 = (i & 63) * 4;
                float4 val = *reinterpret_cast<const float4*>(&ostage[vdw][off4]);
                *reinterpret_cast<float4*>(
                    out + (size_t)b * (C_ * M_) + (size_t)vdw * 4096 + mb4 + off4) = val;
            }
            __syncthreads();
        }
    }
}

extern "C" void kernel_launch(void* const* d_in, const int* in_sizes, int n_in,
                              void* d_out, int out_size, void* d_ws, size_t ws_size,
                              hipStream_t stream)
{
    (void)in_sizes; (void)n_in; (void)out_size; (void)ws_size;
    const float* x   = (const float*)d_in[0];
    const float* w   = (const float*)d_in[1];
    const float* qg  = (const float*)d_in[2];
    const float* qb  = (const float*)d_in[3];
    const float* qm  = (const float*)d_in[4];
    const float* qvr = (const float*)d_in[5];
    const float* vg  = (const float*)d_in[6];
    const float* vb  = (const float*)d_in[7];
    const float* vm  = (const float*)d_in[8];
    const float* vvr = (const float*)d_in[9];
    const float* lw  = (const float*)d_in[10];
    const float* lb  = (const float*)d_in[11];
    float* out = (float*)d_out;

    float* ws   = (float*)d_ws;
    float* q_bn = ws;                  // [b][m][n][k]  2,097,152 f
    float* v_bn = ws + 2097152;        // [b][m][vd]    2,097,152 f
    float* k_bf = ws + 4194304;        // [b][k][m]       524,288 f (in-place sm)
    float* clam = ws + 4718592;        // [b][k][vd]       32,768 f

    hipMemsetAsync(clam, 0, 32768 * sizeof(float), stream);
    hipLaunchKernelGGL(k_qkv, dim3(512), dim3(256), 0, stream,
                       x, w, qg, qb, qm, qvr, vg, vb, vm, vvr, q_bn, k_bf, v_bn);
    hipLaunchKernelGGL(k_softmax, dim3(512), dim3(256), 0, stream, k_bf);
    hipLaunchKernelGGL(k_clam, dim3(256), dim3(256), 0, stream, k_bf, v_bn, clam);
    hipLaunchKernelGGL(k_fuse, dim3(256), dim3(512), 0, stream,
                       v_bn, q_bn, clam, lw, lb, out);
}